// Round 1
// baseline (206.899 us; speedup 1.0000x reference)
//
#include <hip/hip_runtime.h>

// Problem constants (from reference): B=4, S=2048, V=64, D=1024, P=8, H=42, K=49152
#define BB 4
#define SS 2048
#define VV 64
#define DD 1024
#define PP 8
#define HH 42
#define KK 49152

static constexpr float F_EPS = 1e-12f;
static constexpr float SQRT_S = 45.254833995939045f;  // sqrt(2048)

// ---------------------------------------------------------------------------
// K1: per (b,s) row: norm + dots with u[p] = e/max(2|e|,eps), emit
//     n[b,s,p] = c / max(sqrt(S)*c, eps), c = relu(dot/max(norm,eps)).
// One wave per row, 4 rows per wave, 16 rows per block. u staged in LDS.
// ---------------------------------------------------------------------------
__global__ __launch_bounds__(256) void k1_rowdots(
    const float* __restrict__ ctx, const float* __restrict__ lora,
    float* __restrict__ n_ws) {
  __shared__ float u_lds[PP * DD];  // 32 KB
  const int t = threadIdx.x;
  for (int i = t; i < PP * DD; i += 256) {
    float e = lora[i];
    u_lds[i] = e / fmaxf(2.0f * fabsf(e), F_EPS);
  }
  __syncthreads();
  const int wave = t >> 6, lane = t & 63;
  const float4* ctx4 = (const float4*)ctx;
  const float4* u4 = (const float4*)u_lds;
  #pragma unroll
  for (int i = 0; i < 4; ++i) {
    const int r = blockIdx.x * 16 + wave * 4 + i;  // r = b*S + s
    float sumsq = 0.0f;
    float dot[PP];
    #pragma unroll
    for (int p = 0; p < PP; ++p) dot[p] = 0.0f;
    #pragma unroll
    for (int j = 0; j < 4; ++j) {
      float4 c = ctx4[(size_t)r * 256 + j * 64 + lane];
      sumsq += c.x * c.x + c.y * c.y + c.z * c.z + c.w * c.w;
      #pragma unroll
      for (int p = 0; p < PP; ++p) {
        float4 u = u4[p * 256 + j * 64 + lane];
        dot[p] += c.x * u.x + c.y * u.y + c.z * u.z + c.w * u.w;
      }
    }
    #pragma unroll
    for (int m = 32; m >= 1; m >>= 1) {
      sumsq += __shfl_xor(sumsq, m, 64);
      #pragma unroll
      for (int p = 0; p < PP; ++p) dot[p] += __shfl_xor(dot[p], m, 64);
    }
    if (lane == 0) {
      float inv = 1.0f / fmaxf(sqrtf(sumsq), F_EPS);
      float nn[PP];
      #pragma unroll
      for (int p = 0; p < PP; ++p) {
        float v = dot[p] * inv;
        float c = fmaxf(v, 0.0f);
        nn[p] = c / fmaxf(SQRT_S * c, F_EPS);
      }
      float4* o = (float4*)(n_ws + (size_t)r * 8);
      o[0] = make_float4(nn[0], nn[1], nn[2], nn[3]);
      o[1] = make_float4(nn[4], nn[5], nn[6], nn[7]);
    }
  }
}

// ---------------------------------------------------------------------------
// K3: per (b, s-chunk of 64): recompute Z[p] (exp-sum over all S; safe with
//     no max-shift since n in [0, 0.0221]), then partial a_v over its chunk.
//     part[b][chunk][p][d]. Thread owns 4 d-columns (float4).
// ---------------------------------------------------------------------------
__global__ __launch_bounds__(256) void k3_av(
    const float* __restrict__ ctx, const float* __restrict__ n_ws,
    float* __restrict__ part) {
  const int t = threadIdx.x;
  const int chunk = blockIdx.x;  // 0..31
  const int b = blockIdx.y;      // 0..3
  __shared__ float zpart[4][PP];
  __shared__ float Zl[PP];
  __shared__ float w_lds[64 * PP];
  float z[PP];
  #pragma unroll
  for (int p = 0; p < PP; ++p) z[p] = 0.0f;
  const float4* n4 = (const float4*)n_ws;
  for (int it = 0; it < 8; ++it) {
    int s = it * 256 + t;
    float4 a = n4[(size_t)(b * SS + s) * 2];
    float4 c = n4[(size_t)(b * SS + s) * 2 + 1];
    z[0] += expf(a.x); z[1] += expf(a.y); z[2] += expf(a.z); z[3] += expf(a.w);
    z[4] += expf(c.x); z[5] += expf(c.y); z[6] += expf(c.z); z[7] += expf(c.w);
  }
  #pragma unroll
  for (int m = 32; m >= 1; m >>= 1) {
    #pragma unroll
    for (int p = 0; p < PP; ++p) z[p] += __shfl_xor(z[p], m, 64);
  }
  const int wave = t >> 6, lane = t & 63;
  if (lane == 0) {
    #pragma unroll
    for (int p = 0; p < PP; ++p) zpart[wave][p] = z[p];
  }
  __syncthreads();
  if (t < PP) Zl[t] = zpart[0][t] + zpart[1][t] + zpart[2][t] + zpart[3][t];
  __syncthreads();
  if (t < 64) {
    int s = chunk * 64 + t;
    #pragma unroll
    for (int p = 0; p < PP; ++p)
      w_lds[t * PP + p] = expf(n_ws[(size_t)(b * SS + s) * 8 + p]) / Zl[p];
  }
  __syncthreads();
  float4 acc[PP];
  #pragma unroll
  for (int p = 0; p < PP; ++p) acc[p] = make_float4(0.f, 0.f, 0.f, 0.f);
  const float4* ctx4 = (const float4*)ctx;
  const float4* w4 = (const float4*)w_lds;
  for (int sl = 0; sl < 64; ++sl) {
    int s = chunk * 64 + sl;
    float4 c = ctx4[(size_t)(b * SS + s) * 256 + t];
    float4 wa = w4[sl * 2];
    float4 wb = w4[sl * 2 + 1];
    float w[PP] = {wa.x, wa.y, wa.z, wa.w, wb.x, wb.y, wb.z, wb.w};
    #pragma unroll
    for (int p = 0; p < PP; ++p) {
      acc[p].x += w[p] * c.x;
      acc[p].y += w[p] * c.y;
      acc[p].z += w[p] * c.z;
      acc[p].w += w[p] * c.w;
    }
  }
  float4* part4 = (float4*)part;
  #pragma unroll
  for (int p = 0; p < PP; ++p)
    part4[(size_t)((b * 32 + chunk) * PP + p) * 256 + t] = acc[p];
}

// ---------------------------------------------------------------------------
// K4: per (p,b): reduce 32 partials -> a_v, cos = <e,a_v>/max(|e||a_v|,1e-8)
// ---------------------------------------------------------------------------
__global__ __launch_bounds__(256) void k4_cos(
    const float* __restrict__ part, const float* __restrict__ lora,
    float* __restrict__ cos_ws) {
  const int t = threadIdx.x;
  const int p = blockIdx.x, b = blockIdx.y;
  const float4* part4 = (const float4*)part;
  float4 av = make_float4(0.f, 0.f, 0.f, 0.f);
  for (int c = 0; c < 32; ++c) {
    float4 x = part4[(size_t)((b * 32 + c) * PP + p) * 256 + t];
    av.x += x.x; av.y += x.y; av.z += x.z; av.w += x.w;
  }
  float4 e = ((const float4*)lora)[p * 256 + t];
  float dt = av.x * e.x + av.y * e.y + av.z * e.z + av.w * e.w;
  float a2 = av.x * av.x + av.y * av.y + av.z * av.z + av.w * av.w;
  float e2 = e.x * e.x + e.y * e.y + e.z * e.z + e.w * e.w;
  #pragma unroll
  for (int m = 32; m >= 1; m >>= 1) {
    dt += __shfl_xor(dt, m, 64);
    a2 += __shfl_xor(a2, m, 64);
    e2 += __shfl_xor(e2, m, 64);
  }
  __shared__ float red[4][3];
  const int wave = t >> 6, lane = t & 63;
  if (lane == 0) { red[wave][0] = dt; red[wave][1] = a2; red[wave][2] = e2; }
  __syncthreads();
  if (t == 0) {
    float Dv = red[0][0] + red[1][0] + red[2][0] + red[3][0];
    float Av = red[0][1] + red[1][1] + red[2][1] + red[3][1];
    float Ev = red[0][2] + red[1][2] + red[2][2] + red[3][2];
    cos_ws[b * PP + p] = Dv / fmaxf(sqrtf(Ev) * sqrtf(Av), 1e-8f);
  }
}

// ---------------------------------------------------------------------------
// K5: h_all[r][h] = tanh(tables_row[r] . w1[:,h] + b1[h]), r = p*V+v' (512 rows)
// ---------------------------------------------------------------------------
__global__ __launch_bounds__(256) void k5_hall(
    const float* __restrict__ tables, const float* __restrict__ w1,
    const float* __restrict__ b1, float* __restrict__ h_all) {
  __shared__ float w1_lds[128 * HH];   // 21504 B
  __shared__ float row_lds[16 * 128];  // 8192 B
  const int t = threadIdx.x;
  const int r0 = blockIdx.x * 16;
  const int h = t & 63;
  const int rg = t >> 6;
  float acc[4] = {0.f, 0.f, 0.f, 0.f};
  for (int cch = 0; cch < 8; ++cch) {
    const int d0 = cch * 128;
    __syncthreads();
    for (int i = t; i < 128 * HH; i += 256) w1_lds[i] = w1[d0 * HH + i];
    for (int i = t; i < 16 * 128; i += 256) {
      int rl = i >> 7, dl = i & 127;
      row_lds[i] = tables[(size_t)(r0 + rl) * DD + d0 + dl];
    }
    __syncthreads();
    if (h < HH) {
      for (int dl = 0; dl < 128; ++dl) {
        float wv = w1_lds[dl * HH + h];
        #pragma unroll
        for (int i = 0; i < 4; ++i)
          acc[i] += row_lds[(rg * 4 + i) * 128 + dl] * wv;
      }
    }
  }
  if (h < HH) {
    float bb = b1[h];
    #pragma unroll
    for (int i = 0; i < 4; ++i)
      h_all[(size_t)(r0 + rg * 4 + i) * HH + h] = tanhf(acc[i] + bb);
  }
}

// ---------------------------------------------------------------------------
// K7: out[bv,k] = hg[bv,:] @ w2[:,k] + b2[k], hg = sum_p gate[b,p]*h_all[gather]
// Block = (b, k-tile of 128). Thread computes 8 bv x 4 k from LDS tiles.
// ---------------------------------------------------------------------------
__global__ __launch_bounds__(256) void k7_out(
    const float* __restrict__ w2, const float* __restrict__ b2,
    const float* __restrict__ h_all, const float* __restrict__ cos_ws,
    const int* __restrict__ prefix, float* __restrict__ out) {
  __shared__ float gate_lds[PP];
  __shared__ float hg_lds[HH * 64];    // [h][v]
  __shared__ float w2_lds[HH * 128];   // [h][kk]
  const int t = threadIdx.x;
  const int b = blockIdx.y;
  const size_t kbase = (size_t)blockIdx.x * 128;
  for (int i = t; i < HH * 128; i += 256) {
    int h = i >> 7, kk = i & 127;
    w2_lds[i] = w2[(size_t)h * KK + kbase + kk];
  }
  if (t == 0) {
    float c[PP];
    float m = -1e30f;
    #pragma unroll
    for (int p = 0; p < PP; ++p) { c[p] = cos_ws[b * PP + p]; m = fmaxf(m, c[p]); }
    float s = 0.0f;
    #pragma unroll
    for (int p = 0; p < PP; ++p) { c[p] = expf(c[p] - m); s += c[p]; }
    float inv = 1.0f / s;
    float m2 = -1e30f;
    #pragma unroll
    for (int p = 0; p < PP; ++p) { c[p] *= inv; m2 = fmaxf(m2, c[p]); }
    float s2 = 0.0f;
    #pragma unroll
    for (int p = 0; p < PP; ++p) { c[p] = expf(c[p] - m2); s2 += c[p]; }
    float inv2 = 1.0f / s2;
    #pragma unroll
    for (int p = 0; p < PP; ++p) gate_lds[p] = c[p] * inv2;
  }
  __syncthreads();
  for (int idx = t; idx < 64 * HH; idx += 256) {
    int v = idx / HH;
    int h = idx - v * HH;
    int tokv = prefix[b * VV + v];
    float s = 0.0f;
    #pragma unroll
    for (int p = 0; p < PP; ++p)
      s += gate_lds[p] * h_all[(size_t)(p * VV + tokv) * HH + h];
    hg_lds[h * 64 + v] = s;
  }
  __syncthreads();
  const int tk = t & 31, tb = t >> 5;
  float4 acc[8];
  #pragma unroll
  for (int i = 0; i < 8; ++i) acc[i] = make_float4(0.f, 0.f, 0.f, 0.f);
  const float4* w24 = (const float4*)w2_lds;
  const float4* hg4 = (const float4*)hg_lds;
  #pragma unroll 2
  for (int h = 0; h < HH; ++h) {
    float4 wv = w24[h * 32 + tk];
    float4 g0 = hg4[h * 16 + tb * 2];
    float4 g1 = hg4[h * 16 + tb * 2 + 1];
    float gg[8] = {g0.x, g0.y, g0.z, g0.w, g1.x, g1.y, g1.z, g1.w};
    #pragma unroll
    for (int i = 0; i < 8; ++i) {
      acc[i].x += gg[i] * wv.x;
      acc[i].y += gg[i] * wv.y;
      acc[i].z += gg[i] * wv.z;
      acc[i].w += gg[i] * wv.w;
    }
  }
  float4 b2v = ((const float4*)b2)[(kbase >> 2) + tk];
  float4* out4 = (float4*)out;
  #pragma unroll
  for (int i = 0; i < 8; ++i) {
    int bv = b * 64 + tb * 8 + i;
    float4 o;
    o.x = acc[i].x + b2v.x;
    o.y = acc[i].y + b2v.y;
    o.z = acc[i].z + b2v.z;
    o.w = acc[i].w + b2v.w;
    out4[(((size_t)bv * KK + kbase) >> 2) + tk] = o;
  }
}

extern "C" void kernel_launch(void* const* d_in, const int* in_sizes, int n_in,
                              void* d_out, int out_size, void* d_ws, size_t ws_size,
                              hipStream_t stream) {
  const int* prefix = (const int*)d_in[0];
  const float* ctx = (const float*)d_in[1];
  const float* tables = (const float*)d_in[2];
  const float* lora = (const float*)d_in[3];
  const float* w1 = (const float*)d_in[4];
  const float* b1 = (const float*)d_in[5];
  const float* w2 = (const float*)d_in[6];
  const float* b2 = (const float*)d_in[7];
  float* out = (float*)d_out;
  char* ws = (char*)d_ws;
  // workspace (bytes): n_ws 262144 | part 4194304 | cos 128 | h_all 86016  (~4.5 MB)
  float* n_ws = (float*)ws;
  float* part = (float*)(ws + 262144);
  float* cos_ws = (float*)(ws + 262144 + 4194304);
  float* h_all = (float*)(ws + 262144 + 4194304 + 128);

  k1_rowdots<<<512, 256, 0, stream>>>(ctx, lora, n_ws);
  k5_hall<<<32, 256, 0, stream>>>(tables, w1, b1, h_all);
  k3_av<<<dim3(32, 4), 256, 0, stream>>>(ctx, n_ws, part);
  k4_cos<<<dim3(8, 4), 256, 0, stream>>>(part, lora, cos_ws);
  k7_out<<<dim3(384, 4), 256, 0, stream>>>(w2, b2, h_all, cos_ws, prefix, out);
}

// Round 2
// 169.964 us; speedup vs baseline: 1.2173x; 1.2173x over previous
//
#include <hip/hip_runtime.h>

// Problem constants (from reference): B=4, S=2048, V=64, D=1024, P=8, H=42, K=49152
#define BB 4
#define SS 2048
#define VV 64
#define DD 1024
#define PP 8
#define HH 42
#define KK 49152

static constexpr float F_EPS = 1e-12f;
static constexpr float SQRT_S = 45.254833995939045f;  // sqrt(2048)

// ---------------------------------------------------------------------------
// K1: per (b,s) row: norm + dots with u[p] = e/max(2|e|,eps), emit
//     n[b,s,p] = c / max(sqrt(S)*c, eps), c = relu(dot/max(norm,eps)).
// One wave per row, 4 rows per wave, 16 rows per block. u staged in LDS.
// ---------------------------------------------------------------------------
__global__ __launch_bounds__(256) void k1_rowdots(
    const float* __restrict__ ctx, const float* __restrict__ lora,
    float* __restrict__ n_ws) {
  __shared__ float u_lds[PP * DD];  // 32 KB
  const int t = threadIdx.x;
  for (int i = t; i < PP * DD; i += 256) {
    float e = lora[i];
    u_lds[i] = e / fmaxf(2.0f * fabsf(e), F_EPS);
  }
  __syncthreads();
  const int wave = t >> 6, lane = t & 63;
  const float4* ctx4 = (const float4*)ctx;
  const float4* u4 = (const float4*)u_lds;
  #pragma unroll
  for (int i = 0; i < 4; ++i) {
    const int r = blockIdx.x * 16 + wave * 4 + i;  // r = b*S + s
    float sumsq = 0.0f;
    float dot[PP];
    #pragma unroll
    for (int p = 0; p < PP; ++p) dot[p] = 0.0f;
    #pragma unroll
    for (int j = 0; j < 4; ++j) {
      float4 c = ctx4[(size_t)r * 256 + j * 64 + lane];
      sumsq += c.x * c.x + c.y * c.y + c.z * c.z + c.w * c.w;
      #pragma unroll
      for (int p = 0; p < PP; ++p) {
        float4 u = u4[p * 256 + j * 64 + lane];
        dot[p] += c.x * u.x + c.y * u.y + c.z * u.z + c.w * u.w;
      }
    }
    #pragma unroll
    for (int m = 32; m >= 1; m >>= 1) {
      sumsq += __shfl_xor(sumsq, m, 64);
      #pragma unroll
      for (int p = 0; p < PP; ++p) dot[p] += __shfl_xor(dot[p], m, 64);
    }
    if (lane == 0) {
      float inv = 1.0f / fmaxf(sqrtf(sumsq), F_EPS);
      float nn[PP];
      #pragma unroll
      for (int p = 0; p < PP; ++p) {
        float v = dot[p] * inv;
        float c = fmaxf(v, 0.0f);
        nn[p] = c / fmaxf(SQRT_S * c, F_EPS);
      }
      float4* o = (float4*)(n_ws + (size_t)r * 8);
      o[0] = make_float4(nn[0], nn[1], nn[2], nn[3]);
      o[1] = make_float4(nn[4], nn[5], nn[6], nn[7]);
    }
  }
}

// ---------------------------------------------------------------------------
// K3: per (b, s-chunk of 64, d-half of 512): recompute Z[p] (exp-sum over all
//     S; safe with no max-shift since n in [0, 0.0221]), then partial a_v over
//     its chunk/d-half. part[b][chunk][p][d]. Thread owns 2 d-cols (float2).
//     grid (32,4,2) = 256 blocks -> one per CU.
// ---------------------------------------------------------------------------
__global__ __launch_bounds__(256) void k3_av(
    const float* __restrict__ ctx, const float* __restrict__ n_ws,
    float* __restrict__ part) {
  const int t = threadIdx.x;
  const int chunk = blockIdx.x;  // 0..31
  const int b = blockIdx.y;      // 0..3
  const int dz = blockIdx.z;     // 0..1 (d-half)
  __shared__ float zpart[4][PP];
  __shared__ float Zl[PP];
  __shared__ float w_lds[64 * PP];
  float z[PP];
  #pragma unroll
  for (int p = 0; p < PP; ++p) z[p] = 0.0f;
  const float4* n4 = (const float4*)n_ws;
  for (int it = 0; it < 8; ++it) {
    int s = it * 256 + t;
    float4 a = n4[(size_t)(b * SS + s) * 2];
    float4 c = n4[(size_t)(b * SS + s) * 2 + 1];
    z[0] += expf(a.x); z[1] += expf(a.y); z[2] += expf(a.z); z[3] += expf(a.w);
    z[4] += expf(c.x); z[5] += expf(c.y); z[6] += expf(c.z); z[7] += expf(c.w);
  }
  #pragma unroll
  for (int m = 32; m >= 1; m >>= 1) {
    #pragma unroll
    for (int p = 0; p < PP; ++p) z[p] += __shfl_xor(z[p], m, 64);
  }
  const int wave = t >> 6, lane = t & 63;
  if (lane == 0) {
    #pragma unroll
    for (int p = 0; p < PP; ++p) zpart[wave][p] = z[p];
  }
  __syncthreads();
  if (t < PP) Zl[t] = zpart[0][t] + zpart[1][t] + zpart[2][t] + zpart[3][t];
  __syncthreads();
  if (t < 64) {
    int s = chunk * 64 + t;
    #pragma unroll
    for (int p = 0; p < PP; ++p)
      w_lds[t * PP + p] = expf(n_ws[(size_t)(b * SS + s) * 8 + p]) / Zl[p];
  }
  __syncthreads();
  float2 acc[PP];
  #pragma unroll
  for (int p = 0; p < PP; ++p) acc[p] = make_float2(0.f, 0.f);
  const float2* ctx2 = (const float2*)ctx;
  const float4* w4 = (const float4*)w_lds;
  #pragma unroll 4
  for (int sl = 0; sl < 64; ++sl) {
    int s = chunk * 64 + sl;
    float2 c = ctx2[(size_t)(b * SS + s) * 512 + dz * 256 + t];
    float4 wa = w4[sl * 2];
    float4 wb = w4[sl * 2 + 1];
    float w[PP] = {wa.x, wa.y, wa.z, wa.w, wb.x, wb.y, wb.z, wb.w};
    #pragma unroll
    for (int p = 0; p < PP; ++p) {
      acc[p].x += w[p] * c.x;
      acc[p].y += w[p] * c.y;
    }
  }
  float2* part2 = (float2*)part;
  #pragma unroll
  for (int p = 0; p < PP; ++p)
    part2[(size_t)((b * 32 + chunk) * PP + p) * 512 + dz * 256 + t] = acc[p];
}

// ---------------------------------------------------------------------------
// K4: per (p,b): reduce 32 partials -> a_v, cos = <e,a_v>/max(|e||a_v|,1e-8)
// ---------------------------------------------------------------------------
__global__ __launch_bounds__(256) void k4_cos(
    const float* __restrict__ part, const float* __restrict__ lora,
    float* __restrict__ cos_ws) {
  const int t = threadIdx.x;
  const int p = blockIdx.x, b = blockIdx.y;
  const float4* part4 = (const float4*)part;
  float4 av = make_float4(0.f, 0.f, 0.f, 0.f);
  for (int c = 0; c < 32; ++c) {
    float4 x = part4[(size_t)((b * 32 + c) * PP + p) * 256 + t];
    av.x += x.x; av.y += x.y; av.z += x.z; av.w += x.w;
  }
  float4 e = ((const float4*)lora)[p * 256 + t];
  float dt = av.x * e.x + av.y * e.y + av.z * e.z + av.w * e.w;
  float a2 = av.x * av.x + av.y * av.y + av.z * av.z + av.w * av.w;
  float e2 = e.x * e.x + e.y * e.y + e.z * e.z + e.w * e.w;
  #pragma unroll
  for (int m = 32; m >= 1; m >>= 1) {
    dt += __shfl_xor(dt, m, 64);
    a2 += __shfl_xor(a2, m, 64);
    e2 += __shfl_xor(e2, m, 64);
  }
  __shared__ float red[4][3];
  const int wave = t >> 6, lane = t & 63;
  if (lane == 0) { red[wave][0] = dt; red[wave][1] = a2; red[wave][2] = e2; }
  __syncthreads();
  if (t == 0) {
    float Dv = red[0][0] + red[1][0] + red[2][0] + red[3][0];
    float Av = red[0][1] + red[1][1] + red[2][1] + red[3][1];
    float Ev = red[0][2] + red[1][2] + red[2][2] + red[3][2];
    cos_ws[b * PP + p] = Dv / fmaxf(sqrtf(Ev) * sqrtf(Av), 1e-8f);
  }
}

// ---------------------------------------------------------------------------
// K5: h_all[r][h] = tanh(tables_row[r] . w1[:,h] + b1[h]), r = p*V+v' (512 rows)
// One block per row (512 blocks = 2/CU). Thread (h=t&63, q=t>>6) does a
// 256-long partial dot; w1 read from global (172 KB, L2-resident); row in LDS.
// ---------------------------------------------------------------------------
__global__ __launch_bounds__(256) void k5_hall(
    const float* __restrict__ tables, const float* __restrict__ w1,
    const float* __restrict__ b1, float* __restrict__ h_all) {
  __shared__ float row_lds[DD];        // 4 KB
  __shared__ float partial[4 * 64];    // 1 KB
  const int t = threadIdx.x;
  const int r = blockIdx.x;
  ((float4*)row_lds)[t] = ((const float4*)(tables + (size_t)r * DD))[t];
  __syncthreads();
  const int h = t & 63, q = t >> 6;
  float acc = 0.0f;
  if (h < HH) {
    const int d0 = q * 256;
    #pragma unroll 8
    for (int dl = 0; dl < 256; ++dl) {
      acc += row_lds[d0 + dl] * w1[(size_t)(d0 + dl) * HH + h];
    }
  }
  partial[q * 64 + h] = acc;
  __syncthreads();
  if (t < HH) {
    float s = partial[t] + partial[64 + t] + partial[128 + t] + partial[192 + t];
    h_all[(size_t)r * HH + t] = tanhf(s + b1[t]);
  }
}

// ---------------------------------------------------------------------------
// K7: out[bv,k] = hg[bv,:] @ w2[:,k] + b2[k], hg = sum_p gate[b,p]*h_all[gather]
// Block = (b, k-tile of 128). Thread computes 8 bv x 4 k from LDS tiles.
// ---------------------------------------------------------------------------
__global__ __launch_bounds__(256) void k7_out(
    const float* __restrict__ w2, const float* __restrict__ b2,
    const float* __restrict__ h_all, const float* __restrict__ cos_ws,
    const int* __restrict__ prefix, float* __restrict__ out) {
  __shared__ float gate_lds[PP];
  __shared__ float hg_lds[HH * 64];    // [h][v]
  __shared__ float w2_lds[HH * 128];   // [h][kk]
  const int t = threadIdx.x;
  const int b = blockIdx.y;
  const size_t kbase = (size_t)blockIdx.x * 128;
  for (int i = t; i < HH * 128; i += 256) {
    int h = i >> 7, kk = i & 127;
    w2_lds[i] = w2[(size_t)h * KK + kbase + kk];
  }
  if (t == 0) {
    float c[PP];
    float m = -1e30f;
    #pragma unroll
    for (int p = 0; p < PP; ++p) { c[p] = cos_ws[b * PP + p]; m = fmaxf(m, c[p]); }
    float s = 0.0f;
    #pragma unroll
    for (int p = 0; p < PP; ++p) { c[p] = expf(c[p] - m); s += c[p]; }
    float inv = 1.0f / s;
    float m2 = -1e30f;
    #pragma unroll
    for (int p = 0; p < PP; ++p) { c[p] *= inv; m2 = fmaxf(m2, c[p]); }
    float s2 = 0.0f;
    #pragma unroll
    for (int p = 0; p < PP; ++p) { c[p] = expf(c[p] - m2); s2 += c[p]; }
    float inv2 = 1.0f / s2;
    #pragma unroll
    for (int p = 0; p < PP; ++p) gate_lds[p] = c[p] * inv2;
  }
  __syncthreads();
  for (int idx = t; idx < 64 * HH; idx += 256) {
    int v = idx / HH;
    int h = idx - v * HH;
    int tokv = prefix[b * VV + v];
    float s = 0.0f;
    #pragma unroll
    for (int p = 0; p < PP; ++p)
      s += gate_lds[p] * h_all[(size_t)(p * VV + tokv) * HH + h];
    hg_lds[h * 64 + v] = s;
  }
  __syncthreads();
  const int tk = t & 31, tb = t >> 5;
  float4 acc[8];
  #pragma unroll
  for (int i = 0; i < 8; ++i) acc[i] = make_float4(0.f, 0.f, 0.f, 0.f);
  const float4* w24 = (const float4*)w2_lds;
  const float4* hg4 = (const float4*)hg_lds;
  #pragma unroll 2
  for (int h = 0; h < HH; ++h) {
    float4 wv = w24[h * 32 + tk];
    float4 g0 = hg4[h * 16 + tb * 2];
    float4 g1 = hg4[h * 16 + tb * 2 + 1];
    float gg[8] = {g0.x, g0.y, g0.z, g0.w, g1.x, g1.y, g1.z, g1.w};
    #pragma unroll
    for (int i = 0; i < 8; ++i) {
      acc[i].x += gg[i] * wv.x;
      acc[i].y += gg[i] * wv.y;
      acc[i].z += gg[i] * wv.z;
      acc[i].w += gg[i] * wv.w;
    }
  }
  float4 b2v = ((const float4*)b2)[(kbase >> 2) + tk];
  float4* out4 = (float4*)out;
  #pragma unroll
  for (int i = 0; i < 8; ++i) {
    int bv = b * 64 + tb * 8 + i;
    float4 o;
    o.x = acc[i].x + b2v.x;
    o.y = acc[i].y + b2v.y;
    o.z = acc[i].z + b2v.z;
    o.w = acc[i].w + b2v.w;
    out4[(((size_t)bv * KK + kbase) >> 2) + tk] = o;
  }
}

extern "C" void kernel_launch(void* const* d_in, const int* in_sizes, int n_in,
                              void* d_out, int out_size, void* d_ws, size_t ws_size,
                              hipStream_t stream) {
  const int* prefix = (const int*)d_in[0];
  const float* ctx = (const float*)d_in[1];
  const float* tables = (const float*)d_in[2];
  const float* lora = (const float*)d_in[3];
  const float* w1 = (const float*)d_in[4];
  const float* b1 = (const float*)d_in[5];
  const float* w2 = (const float*)d_in[6];
  const float* b2 = (const float*)d_in[7];
  float* out = (float*)d_out;
  char* ws = (char*)d_ws;
  // workspace (bytes): n_ws 262144 | part 4194304 | cos 128 | h_all 86016  (~4.5 MB)
  float* n_ws = (float*)ws;
  float* part = (float*)(ws + 262144);
  float* cos_ws = (float*)(ws + 262144 + 4194304);
  float* h_all = (float*)(ws + 262144 + 4194304 + 128);

  k1_rowdots<<<512, 256, 0, stream>>>(ctx, lora, n_ws);
  k5_hall<<<512, 256, 0, stream>>>(tables, w1, b1, h_all);
  k3_av<<<dim3(32, 4, 2), 256, 0, stream>>>(ctx, n_ws, part);
  k4_cos<<<dim3(8, 4), 256, 0, stream>>>(part, lora, cos_ws);
  k7_out<<<dim3(384, 4), 256, 0, stream>>>(w2, b2, h_all, cos_ws, prefix, out);
}

// Round 3
// 161.874 us; speedup vs baseline: 1.2781x; 1.0500x over previous
//
#include <hip/hip_runtime.h>

// Problem constants (from reference): B=4, S=2048, V=64, D=1024, P=8, H=42, K=49152
#define BB 4
#define SS 2048
#define VV 64
#define DD 1024
#define PP 8
#define HH 42
#define KK 49152

static constexpr float F_EPS = 1e-12f;
static constexpr float SQRT_S = 45.254833995939045f;  // sqrt(2048)

// ---------------------------------------------------------------------------
// K15 fused: blocks [0,512) do k1 (row dots -> n), blocks [512,1024) do k5
// (h_all). Block-uniform branch, both 256 threads.
//
// k1 part: wave w handles rows rbase..rbase+3. u staged in LDS (32 KB),
// read 32 b128/wave (j-outer loop). Reduction: two-phase — 3 butterfly
// levels on 8 dots within groups of 8 lanes, lane-select dot[lane&7],
// 3 cross-group levels; sumsq full 6-level butterfly. 33 swizzles/row
// (vs 54) and 32 u-reads/wave (vs 128).
// ---------------------------------------------------------------------------
__global__ __launch_bounds__(256) void k15_fused(
    const float* __restrict__ ctx, const float* __restrict__ lora,
    const float* __restrict__ tables, const float* __restrict__ w1,
    const float* __restrict__ b1, float* __restrict__ n_ws,
    float* __restrict__ h_all) {
  __shared__ float smem[PP * DD];  // 32 KB; k5 aliases first 5 KB
  const int t = threadIdx.x;
  if (blockIdx.x < 512) {
    // ---------------- k1: row dots ----------------
    for (int i = t; i < PP * DD; i += 256) {
      float e = lora[i];
      smem[i] = e / fmaxf(2.0f * fabsf(e), F_EPS);
    }
    __syncthreads();
    const int wave = t >> 6, lane = t & 63;
    const int rbase = blockIdx.x * 16 + wave * 4;
    const float4* ctx4 = (const float4*)ctx;
    const float4* u4 = (const float4*)smem;
    float dot[4][PP];
    float sq[4] = {0.f, 0.f, 0.f, 0.f};
    #pragma unroll
    for (int i = 0; i < 4; ++i)
      #pragma unroll
      for (int p = 0; p < PP; ++p) dot[i][p] = 0.f;
    #pragma unroll
    for (int j = 0; j < 4; ++j) {
      float4 c[4];
      #pragma unroll
      for (int i = 0; i < 4; ++i)
        c[i] = ctx4[(size_t)(rbase + i) * 256 + j * 64 + lane];
      #pragma unroll
      for (int i = 0; i < 4; ++i)
        sq[i] += c[i].x * c[i].x + c[i].y * c[i].y + c[i].z * c[i].z + c[i].w * c[i].w;
      #pragma unroll
      for (int p = 0; p < PP; ++p) {
        float4 u = u4[p * 256 + j * 64 + lane];
        #pragma unroll
        for (int i = 0; i < 4; ++i)
          dot[i][p] += c[i].x * u.x + c[i].y * u.y + c[i].z * u.z + c[i].w * u.w;
      }
    }
    const int sel = lane & 7;
    #pragma unroll
    for (int i = 0; i < 4; ++i) {
      float s = sq[i];
      #pragma unroll
      for (int m = 32; m >= 1; m >>= 1) s += __shfl_xor(s, m, 64);
      float d0 = dot[i][0], d1 = dot[i][1], d2 = dot[i][2], d3 = dot[i][3];
      float d4 = dot[i][4], d5 = dot[i][5], d6 = dot[i][6], d7 = dot[i][7];
      #pragma unroll
      for (int m = 1; m <= 4; m <<= 1) {
        d0 += __shfl_xor(d0, m, 64); d1 += __shfl_xor(d1, m, 64);
        d2 += __shfl_xor(d2, m, 64); d3 += __shfl_xor(d3, m, 64);
        d4 += __shfl_xor(d4, m, 64); d5 += __shfl_xor(d5, m, 64);
        d6 += __shfl_xor(d6, m, 64); d7 += __shfl_xor(d7, m, 64);
      }
      // lane-select dot[lane&7]; groups of 8 lanes hold group-partials
      float v = d0;
      v = (sel == 1) ? d1 : v; v = (sel == 2) ? d2 : v;
      v = (sel == 3) ? d3 : v; v = (sel == 4) ? d4 : v;
      v = (sel == 5) ? d5 : v; v = (sel == 6) ? d6 : v;
      v = (sel == 7) ? d7 : v;
      v += __shfl_xor(v, 8, 64);
      v += __shfl_xor(v, 16, 64);
      v += __shfl_xor(v, 32, 64);
      if (lane < PP) {
        float inv = 1.0f / fmaxf(sqrtf(s), F_EPS);
        float c = fmaxf(v * inv, 0.0f);
        n_ws[(size_t)(rbase + i) * 8 + lane] = c / fmaxf(SQRT_S * c, F_EPS);
      }
    }
  } else {
    // ---------------- k5: h_all row ----------------
    float* row_lds = smem;            // DD floats
    float* partial = smem + DD;       // 256 floats
    const int r = blockIdx.x - 512;
    ((float4*)row_lds)[t] = ((const float4*)(tables + (size_t)r * DD))[t];
    __syncthreads();
    const int h = t & 63, q = t >> 6;
    float acc = 0.0f;
    if (h < HH) {
      const int d0 = q * 256;
      #pragma unroll 8
      for (int dl = 0; dl < 256; ++dl) {
        acc += row_lds[d0 + dl] * w1[(size_t)(d0 + dl) * HH + h];
      }
    }
    partial[q * 64 + h] = acc;
    __syncthreads();
    if (t < HH) {
      float s = partial[t] + partial[64 + t] + partial[128 + t] + partial[192 + t];
      h_all[(size_t)r * HH + t] = tanhf(s + b1[t]);
    }
  }
}

// ---------------------------------------------------------------------------
// K3: per (b, s-chunk of 64, d-half of 512): recompute Z[p] (exp-sum over all
//     S; safe with no max-shift since n in [0, 0.0221]), then partial a_v over
//     its chunk/d-half. part[b][chunk][p][d]. Thread owns 2 d-cols (float2).
// ---------------------------------------------------------------------------
__global__ __launch_bounds__(256) void k3_av(
    const float* __restrict__ ctx, const float* __restrict__ n_ws,
    float* __restrict__ part) {
  const int t = threadIdx.x;
  const int chunk = blockIdx.x;  // 0..31
  const int b = blockIdx.y;      // 0..3
  const int dz = blockIdx.z;     // 0..1 (d-half)
  __shared__ float zpart[4][PP];
  __shared__ float Zl[PP];
  __shared__ float w_lds[64 * PP];
  float z[PP];
  #pragma unroll
  for (int p = 0; p < PP; ++p) z[p] = 0.0f;
  const float4* n4 = (const float4*)n_ws;
  for (int it = 0; it < 8; ++it) {
    int s = it * 256 + t;
    float4 a = n4[(size_t)(b * SS + s) * 2];
    float4 c = n4[(size_t)(b * SS + s) * 2 + 1];
    z[0] += expf(a.x); z[1] += expf(a.y); z[2] += expf(a.z); z[3] += expf(a.w);
    z[4] += expf(c.x); z[5] += expf(c.y); z[6] += expf(c.z); z[7] += expf(c.w);
  }
  #pragma unroll
  for (int m = 32; m >= 1; m >>= 1) {
    #pragma unroll
    for (int p = 0; p < PP; ++p) z[p] += __shfl_xor(z[p], m, 64);
  }
  const int wave = t >> 6, lane = t & 63;
  if (lane == 0) {
    #pragma unroll
    for (int p = 0; p < PP; ++p) zpart[wave][p] = z[p];
  }
  __syncthreads();
  if (t < PP) Zl[t] = zpart[0][t] + zpart[1][t] + zpart[2][t] + zpart[3][t];
  __syncthreads();
  if (t < 64) {
    int s = chunk * 64 + t;
    #pragma unroll
    for (int p = 0; p < PP; ++p)
      w_lds[t * PP + p] = expf(n_ws[(size_t)(b * SS + s) * 8 + p]) / Zl[p];
  }
  __syncthreads();
  float2 acc[PP];
  #pragma unroll
  for (int p = 0; p < PP; ++p) acc[p] = make_float2(0.f, 0.f);
  const float2* ctx2 = (const float2*)ctx;
  const float4* w4 = (const float4*)w_lds;
  #pragma unroll 4
  for (int sl = 0; sl < 64; ++sl) {
    int s = chunk * 64 + sl;
    float2 c = ctx2[(size_t)(b * SS + s) * 512 + dz * 256 + t];
    float4 wa = w4[sl * 2];
    float4 wb = w4[sl * 2 + 1];
    float w[PP] = {wa.x, wa.y, wa.z, wa.w, wb.x, wb.y, wb.z, wb.w};
    #pragma unroll
    for (int p = 0; p < PP; ++p) {
      acc[p].x += w[p] * c.x;
      acc[p].y += w[p] * c.y;
    }
  }
  float2* part2 = (float2*)part;
  #pragma unroll
  for (int p = 0; p < PP; ++p)
    part2[(size_t)((b * 32 + chunk) * PP + p) * 512 + dz * 256 + t] = acc[p];
}

// ---------------------------------------------------------------------------
// K4: per (p,b): reduce 32 partials -> a_v, cos = <e,a_v>/max(|e||a_v|,1e-8)
// ---------------------------------------------------------------------------
__global__ __launch_bounds__(256) void k4_cos(
    const float* __restrict__ part, const float* __restrict__ lora,
    float* __restrict__ cos_ws) {
  const int t = threadIdx.x;
  const int p = blockIdx.x, b = blockIdx.y;
  const float4* part4 = (const float4*)part;
  float4 av = make_float4(0.f, 0.f, 0.f, 0.f);
  #pragma unroll 8
  for (int c = 0; c < 32; ++c) {
    float4 x = part4[(size_t)((b * 32 + c) * PP + p) * 256 + t];
    av.x += x.x; av.y += x.y; av.z += x.z; av.w += x.w;
  }
  float4 e = ((const float4*)lora)[p * 256 + t];
  float dt = av.x * e.x + av.y * e.y + av.z * e.z + av.w * e.w;
  float a2 = av.x * av.x + av.y * av.y + av.z * av.z + av.w * av.w;
  float e2 = e.x * e.x + e.y * e.y + e.z * e.z + e.w * e.w;
  #pragma unroll
  for (int m = 32; m >= 1; m >>= 1) {
    dt += __shfl_xor(dt, m, 64);
    a2 += __shfl_xor(a2, m, 64);
    e2 += __shfl_xor(e2, m, 64);
  }
  __shared__ float red[4][3];
  const int wave = t >> 6, lane = t & 63;
  if (lane == 0) { red[wave][0] = dt; red[wave][1] = a2; red[wave][2] = e2; }
  __syncthreads();
  if (t == 0) {
    float Dv = red[0][0] + red[1][0] + red[2][0] + red[3][0];
    float Av = red[0][1] + red[1][1] + red[2][1] + red[3][1];
    float Ev = red[0][2] + red[1][2] + red[2][2] + red[3][2];
    cos_ws[b * PP + p] = Dv / fmaxf(sqrtf(Ev) * sqrtf(Av), 1e-8f);
  }
}

// ---------------------------------------------------------------------------
// K7: out[bv,k] = hg[bv,:] @ w2[:,k] + b2[k], hg = sum_p gate[b,p]*h_all[gather]
// Block = (b, k-tile of 128). Thread computes 8 bv x 4 k from LDS tiles.
// ---------------------------------------------------------------------------
__global__ __launch_bounds__(256) void k7_out(
    const float* __restrict__ w2, const float* __restrict__ b2,
    const float* __restrict__ h_all, const float* __restrict__ cos_ws,
    const int* __restrict__ prefix, float* __restrict__ out) {
  __shared__ float gate_lds[PP];
  __shared__ float hg_lds[HH * 64];    // [h][v]
  __shared__ float w2_lds[HH * 128];   // [h][kk]
  const int t = threadIdx.x;
  const int b = blockIdx.y;
  const size_t kbase = (size_t)blockIdx.x * 128;
  for (int i = t; i < HH * 128; i += 256) {
    int h = i >> 7, kk = i & 127;
    w2_lds[i] = w2[(size_t)h * KK + kbase + kk];
  }
  if (t == 0) {
    float c[PP];
    float m = -1e30f;
    #pragma unroll
    for (int p = 0; p < PP; ++p) { c[p] = cos_ws[b * PP + p]; m = fmaxf(m, c[p]); }
    float s = 0.0f;
    #pragma unroll
    for (int p = 0; p < PP; ++p) { c[p] = expf(c[p] - m); s += c[p]; }
    float inv = 1.0f / s;
    float m2 = -1e30f;
    #pragma unroll
    for (int p = 0; p < PP; ++p) { c[p] *= inv; m2 = fmaxf(m2, c[p]); }
    float s2 = 0.0f;
    #pragma unroll
    for (int p = 0; p < PP; ++p) { c[p] = expf(c[p] - m2); s2 += c[p]; }
    float inv2 = 1.0f / s2;
    #pragma unroll
    for (int p = 0; p < PP; ++p) gate_lds[p] = c[p] * inv2;
  }
  __syncthreads();
  for (int idx = t; idx < 64 * HH; idx += 256) {
    int v = idx / HH;
    int h = idx - v * HH;
    int tokv = prefix[b * VV + v];
    float s = 0.0f;
    #pragma unroll
    for (int p = 0; p < PP; ++p)
      s += gate_lds[p] * h_all[(size_t)(p * VV + tokv) * HH + h];
    hg_lds[h * 64 + v] = s;
  }
  __syncthreads();
  const int tk = t & 31, tb = t >> 5;
  float4 acc[8];
  #pragma unroll
  for (int i = 0; i < 8; ++i) acc[i] = make_float4(0.f, 0.f, 0.f, 0.f);
  const float4* w24 = (const float4*)w2_lds;
  const float4* hg4 = (const float4*)hg_lds;
  #pragma unroll 2
  for (int h = 0; h < HH; ++h) {
    float4 wv = w24[h * 32 + tk];
    float4 g0 = hg4[h * 16 + tb * 2];
    float4 g1 = hg4[h * 16 + tb * 2 + 1];
    float gg[8] = {g0.x, g0.y, g0.z, g0.w, g1.x, g1.y, g1.z, g1.w};
    #pragma unroll
    for (int i = 0; i < 8; ++i) {
      acc[i].x += gg[i] * wv.x;
      acc[i].y += gg[i] * wv.y;
      acc[i].z += gg[i] * wv.z;
      acc[i].w += gg[i] * wv.w;
    }
  }
  float4 b2v = ((const float4*)b2)[(kbase >> 2) + tk];
  float4* out4 = (float4*)out;
  #pragma unroll
  for (int i = 0; i < 8; ++i) {
    int bv = b * 64 + tb * 8 + i;
    float4 o;
    o.x = acc[i].x + b2v.x;
    o.y = acc[i].y + b2v.y;
    o.z = acc[i].z + b2v.z;
    o.w = acc[i].w + b2v.w;
    out4[(((size_t)bv * KK + kbase) >> 2) + tk] = o;
  }
}

extern "C" void kernel_launch(void* const* d_in, const int* in_sizes, int n_in,
                              void* d_out, int out_size, void* d_ws, size_t ws_size,
                              hipStream_t stream) {
  const int* prefix = (const int*)d_in[0];
  const float* ctx = (const float*)d_in[1];
  const float* tables = (const float*)d_in[2];
  const float* lora = (const float*)d_in[3];
  const float* w1 = (const float*)d_in[4];
  const float* b1 = (const float*)d_in[5];
  const float* w2 = (const float*)d_in[6];
  const float* b2 = (const float*)d_in[7];
  float* out = (float*)d_out;
  char* ws = (char*)d_ws;
  // workspace (bytes): n_ws 262144 | part 4194304 | cos 128 | h_all 86016  (~4.5 MB)
  float* n_ws = (float*)ws;
  float* part = (float*)(ws + 262144);
  float* cos_ws = (float*)(ws + 262144 + 4194304);
  float* h_all = (float*)(ws + 262144 + 4194304 + 128);

  k15_fused<<<1024, 256, 0, stream>>>(ctx, lora, tables, w1, b1, n_ws, h_all);
  k3_av<<<dim3(32, 4, 2), 256, 0, stream>>>(ctx, n_ws, part);
  k4_cos<<<dim3(8, 4), 256, 0, stream>>>(part, lora, cos_ws);
  k7_out<<<dim3(384, 4), 256, 0, stream>>>(w2, b2, h_all, cos_ws, prefix, out);
}